// Round 11
// baseline (627.777 us; speedup 1.0000x reference)
//
#include <hip/hip_runtime.h>
#include <hip/hip_bf16.h>
#include <math.h>

#define NN 100000
#define EE 1600000
#define FF 128
#define HH 64
#define CC 40

constexpr int SCAN_B = 1024;
constexpr int NB = (NN + SCAN_B - 1) / SCAN_B;  // 98

typedef unsigned long long u64;
typedef float f32x4 __attribute__((ext_vector_type(4)));

// 125 dst-range buckets of 800 nodes each (125*800 == 100000 exactly).
constexpr int NBUK = 125;
constexpr int RNB = 800;
constexpr int BCAP3 = 13800;
constexpr int NE_BLK = 4000;
constexpr int ABLK = EE / NE_BLK;   // 400 blocks

__global__ void k_init(int* __restrict__ bcnt) {
    int i = threadIdx.x;
    if (i < NBUK) bcnt[i] = 0;
}

__global__ __launch_bounds__(256) void k_bucket(const int* __restrict__ ei, int* __restrict__ bcnt,
                                                u64* __restrict__ bpr) {
    __shared__ int lcnt[NBUK], lbase[NBUK], loff[NBUK];
    const int t = threadIdx.x;
    for (int k = t; k < NBUK; k += 256) { lcnt[k] = 0; loff[k] = 0; }
    __syncthreads();
    const int e0 = blockIdx.x * NE_BLK;
    int es[16], ed[16];
#pragma unroll
    for (int k = 0; k < 16; ++k) {
        int idx = t + k * 256;
        if (idx < NE_BLK) {
            es[k] = ei[e0 + idx];
            ed[k] = ei[EE + e0 + idx];
            atomicAdd(&lcnt[ed[k] / RNB], 1);
        }
    }
    __syncthreads();
    for (int k = t; k < NBUK; k += 256) lbase[k] = atomicAdd(&bcnt[k], lcnt[k]);
    __syncthreads();
#pragma unroll
    for (int k = 0; k < 16; ++k) {
        int idx = t + k * 256;
        if (idx < NE_BLK) {
            int b = ed[k] / RNB;
            int pos = lbase[b] + atomicAdd(&loff[b], 1);
            if (pos < BCAP3) {
                bpr[(size_t)b * BCAP3 + pos] = (u64)(unsigned)es[k] | ((u64)(unsigned)ed[k] << 32);
            }
        }
    }
}

__global__ __launch_bounds__(512) void k_count3(const u64* __restrict__ bpr, const int* __restrict__ bcnt,
                                                int* __restrict__ deg) {
    __shared__ int h[RNB];
    const int t = threadIdx.x, b = blockIdx.x;
    for (int k = t; k < RNB; k += 512) h[k] = 0;
    __syncthreads();
    const int cnt = min(bcnt[b], BCAP3);
    const u64* __restrict__ pp = bpr + (size_t)b * BCAP3;
    const int lo = b * RNB;
    for (int i = t; i < cnt; i += 512) atomicAdd(&h[(int)(pp[i] >> 32) - lo], 1);
    __syncthreads();
    for (int k = t; k < RNB; k += 512) deg[lo + k] = h[k] + 1;  // +1 self-loop
}

__global__ void k_dinv(const int* __restrict__ deg, float* __restrict__ dinv) {
    int i = blockIdx.x * 256 + threadIdx.x;
    if (i < NN) dinv[i] = rsqrtf((float)deg[i]);
}

__global__ void k_scanA(const int* __restrict__ deg, int* __restrict__ excl, int* __restrict__ bsum) {
    __shared__ int s[SCAN_B];
    int t = threadIdx.x;
    int g = blockIdx.x * SCAN_B + t;
    int v = (g < NN) ? deg[g] : 0;
    s[t] = v;
    __syncthreads();
    for (int o = 1; o < SCAN_B; o <<= 1) {
        int u = (t >= o) ? s[t - o] : 0;
        __syncthreads();
        s[t] += u;
        __syncthreads();
    }
    if (g < NN) excl[g] = s[t] - v;
    if (t == SCAN_B - 1) bsum[blockIdx.x] = s[t];
}

__global__ void k_scanB(int* __restrict__ bsum) {
    __shared__ int s[128];
    int t = threadIdx.x;
    int v = (t < NB) ? bsum[t] : 0;
    s[t] = v;
    __syncthreads();
    for (int o = 1; o < 128; o <<= 1) {
        int u = (t >= o) ? s[t - o] : 0;
        __syncthreads();
        s[t] += u;
        __syncthreads();
    }
    if (t < NB) bsum[t] = s[t] - v;
}

__global__ void k_scanC(int* __restrict__ rp, const int* __restrict__ bsum) {
    int t = threadIdx.x;
    int g = blockIdx.x * SCAN_B + t;
    if (g < NN) rp[g] = rp[g] + bsum[blockIdx.x];
    if (g == 0) rp[NN] = EE + NN;
}

__global__ __launch_bounds__(512) void k_fill3(const u64* __restrict__ bpr, const int* __restrict__ bcnt,
                                               const int* __restrict__ rp, int* __restrict__ cs) {
    __shared__ int lcur[RNB];
    __shared__ int lbuf[RNB + BCAP3];
    const int t = threadIdx.x, b = blockIdx.x;
    const int lo = b * RNB;
    const int rpl = rp[lo];
    for (int k = t; k < RNB; k += 512) lcur[k] = rp[lo + k] - rpl;
    __syncthreads();
    const int cnt = min(bcnt[b], BCAP3);
    const u64* __restrict__ pp = bpr + (size_t)b * BCAP3;
    for (int i = t; i < cnt; i += 512) {
        u64 u = pp[i];
        int pos = atomicAdd(&lcur[(int)(u >> 32) - lo], 1);
        lbuf[pos] = (int)(unsigned)u;
    }
    __syncthreads();
    for (int k = t; k < RNB; k += 512) {
        int pos = atomicAdd(&lcur[k], 1);
        lbuf[pos] = lo + k;
    }
    __syncthreads();
    const int total = rp[lo + RNB] - rpl;
    for (int i = t; i < total; i += 512) __builtin_nontemporal_store(lbuf[i], cs + rpl + i);
}

template <int K>
__global__ __launch_bounds__(256) void k_gemm(const float* __restrict__ A, const float* __restrict__ W,
                                              const float* __restrict__ dinv, float* __restrict__ Z,
                                              int nrows) {
    constexpr int S = 68;
    __shared__ float wl[64 * 64];
    __shared__ float hl[64 * S];
    const int t = threadIdx.x;
    const int r0 = blockIdx.x * 64;
    const int rg = t >> 4, cg = t & 15;
    float acc[4][4] = {};

    for (int kb = 0; kb < K; kb += 64) {
        {
            const float4* Wv = (const float4*)(W + kb * 64);
            for (int i = t; i < 1024; i += 256) ((float4*)wl)[i] = Wv[i];
        }
        for (int i = t; i < 1024; i += 256) {
            int row = i >> 4, d4 = i & 15;
            float4 v = {0.f, 0.f, 0.f, 0.f};
            if (r0 + row < nrows) v = *(const float4*)(A + (size_t)(r0 + row) * K + kb + d4 * 4);
            *(float4*)(hl + row * S + d4 * 4) = v;
        }
        __syncthreads();
#pragma unroll 8
        for (int d = 0; d < 64; ++d) {
            float4 w4 = *(const float4*)(wl + d * 64 + cg * 4);
#pragma unroll
            for (int i = 0; i < 4; i++) {
                float h = hl[(rg * 4 + i) * S + d];
                acc[i][0] = fmaf(h, w4.x, acc[i][0]);
                acc[i][1] = fmaf(h, w4.y, acc[i][1]);
                acc[i][2] = fmaf(h, w4.z, acc[i][2]);
                acc[i][3] = fmaf(h, w4.w, acc[i][3]);
            }
        }
        __syncthreads();
    }
#pragma unroll
    for (int i = 0; i < 4; i++) {
        int row = r0 + rg * 4 + i;
        if (row < nrows) {
            float dv = dinv[row];
            float4 o = {acc[i][0] * dv, acc[i][1] * dv, acc[i][2] * dv, acc[i][3] * dv};
            *(float4*)(Z + (size_t)row * 64 + cg * 4) = o;
        }
    }
}

__global__ __launch_bounds__(256) void k_prepM(const float* __restrict__ Wq, const float* __restrict__ Wk,
                                               float* __restrict__ M) {
    __shared__ float wk[64 * 65];
    __shared__ float wq[4 * 64];
    const int t = threadIdx.x;
    for (int i = t; i < 1024; i += 256) {
        int r = i >> 4, c4 = i & 15;
        float4 v = ((const float4*)Wk)[i];
        wk[r * 65 + c4 * 4 + 0] = v.x;
        wk[r * 65 + c4 * 4 + 1] = v.y;
        wk[r * 65 + c4 * 4 + 2] = v.z;
        wk[r * 65 + c4 * 4 + 3] = v.w;
    }
    const int rbase = blockIdx.x * 4;
    wq[t] = Wq[rbase * 64 + t];
    __syncthreads();
    const int rr = t >> 6;
    const int c = t & 63;
    float acc = 0.f;
#pragma unroll 8
    for (int e = 0; e < 64; ++e) acc = fmaf(wq[rr * 64 + e], wk[c * 65 + e], acc);
    M[(rbase + rr) * 64 + c] = acc;
}

__global__ __launch_bounds__(256) void k_prop(const float* __restrict__ z, const int* __restrict__ rp,
                                              const int* __restrict__ cs, const float* __restrict__ dinv,
                                              const float* __restrict__ bias, float* __restrict__ out) {
    const int lane = threadIdx.x & 63;
    const int g = lane >> 4;
    const int l4 = lane & 15;
    const int n = blockIdx.x * 16 + (threadIdx.x >> 6) * 4 + g;
    const int beg = rp[n], end = rp[n + 1];
    float4 a0 = {0, 0, 0, 0}, a1 = {0, 0, 0, 0}, a2 = {0, 0, 0, 0}, a3 = {0, 0, 0, 0};
    int i = beg;
    for (; i + 8 <= end; i += 8) {
        int c0 = __builtin_nontemporal_load(cs + i);
        int c1 = __builtin_nontemporal_load(cs + i + 1);
        int c2 = __builtin_nontemporal_load(cs + i + 2);
        int c3 = __builtin_nontemporal_load(cs + i + 3);
        int c4 = __builtin_nontemporal_load(cs + i + 4);
        int c5 = __builtin_nontemporal_load(cs + i + 5);
        int c6 = __builtin_nontemporal_load(cs + i + 6);
        int c7 = __builtin_nontemporal_load(cs + i + 7);
        float4 z0 = *(const float4*)(z + (size_t)(unsigned)c0 * 64 + l4 * 4);
        float4 z1 = *(const float4*)(z + (size_t)(unsigned)c1 * 64 + l4 * 4);
        float4 z2 = *(const float4*)(z + (size_t)(unsigned)c2 * 64 + l4 * 4);
        float4 z3 = *(const float4*)(z + (size_t)(unsigned)c3 * 64 + l4 * 4);
        float4 z4 = *(const float4*)(z + (size_t)(unsigned)c4 * 64 + l4 * 4);
        float4 z5 = *(const float4*)(z + (size_t)(unsigned)c5 * 64 + l4 * 4);
        float4 z6 = *(const float4*)(z + (size_t)(unsigned)c6 * 64 + l4 * 4);
        float4 z7 = *(const float4*)(z + (size_t)(unsigned)c7 * 64 + l4 * 4);
        a0.x += z0.x; a0.y += z0.y; a0.z += z0.z; a0.w += z0.w;
        a1.x += z1.x; a1.y += z1.y; a1.z += z1.z; a1.w += z1.w;
        a2.x += z2.x; a2.y += z2.y; a2.z += z2.z; a2.w += z2.w;
        a3.x += z3.x; a3.y += z3.y; a3.z += z3.z; a3.w += z3.w;
        a0.x += z4.x; a0.y += z4.y; a0.z += z4.z; a0.w += z4.w;
        a1.x += z5.x; a1.y += z5.y; a1.z += z5.z; a1.w += z5.w;
        a2.x += z6.x; a2.y += z6.y; a2.z += z6.z; a2.w += z6.w;
        a3.x += z7.x; a3.y += z7.y; a3.z += z7.z; a3.w += z7.w;
    }
    for (; i + 4 <= end; i += 4) {
        int c0 = __builtin_nontemporal_load(cs + i);
        int c1 = __builtin_nontemporal_load(cs + i + 1);
        int c2 = __builtin_nontemporal_load(cs + i + 2);
        int c3 = __builtin_nontemporal_load(cs + i + 3);
        float4 z0 = *(const float4*)(z + (size_t)(unsigned)c0 * 64 + l4 * 4);
        float4 z1 = *(const float4*)(z + (size_t)(unsigned)c1 * 64 + l4 * 4);
        float4 z2 = *(const float4*)(z + (size_t)(unsigned)c2 * 64 + l4 * 4);
        float4 z3 = *(const float4*)(z + (size_t)(unsigned)c3 * 64 + l4 * 4);
        a0.x += z0.x; a0.y += z0.y; a0.z += z0.z; a0.w += z0.w;
        a1.x += z1.x; a1.y += z1.y; a1.z += z1.z; a1.w += z1.w;
        a2.x += z2.x; a2.y += z2.y; a2.z += z2.z; a2.w += z2.w;
        a3.x += z3.x; a3.y += z3.y; a3.z += z3.z; a3.w += z3.w;
    }
    for (; i < end; ++i) {
        int c = __builtin_nontemporal_load(cs + i);
        float4 zr = *(const float4*)(z + (size_t)(unsigned)c * 64 + l4 * 4);
        a0.x += zr.x; a0.y += zr.y; a0.z += zr.z; a0.w += zr.w;
    }
    const float dn = dinv[n];
    const float4 b4 = *(const float4*)(bias + l4 * 4);
    float4 r;
    r.x = fmaf(dn, (a0.x + a1.x) + (a2.x + a3.x), b4.x);
    r.y = fmaf(dn, (a0.y + a1.y) + (a2.y + a3.y), b4.y);
    r.z = fmaf(dn, (a0.z + a1.z) + (a2.z + a3.z), b4.z);
    r.w = fmaf(dn, (a0.w + a1.w) + (a2.w + a3.w), b4.w);
    r.x = r.x > 0.f ? r.x : 0.f;
    r.y = r.y > 0.f ? r.y : 0.f;
    r.z = r.z > 0.f ? r.z : 0.f;
    r.w = r.w > 0.f ? r.w : 0.f;
    __builtin_nontemporal_store(*(const f32x4*)&r, (f32x4*)(out + (size_t)n * 64 + l4 * 4));
}

// ---- per-thread quadratic form for layers L0, L0+1 (h in regs, M broadcast from LDS) ----
// u_e = sum_d h_d * M[d][e]; s = dot(u, h). All arrays statically indexed (no scratch).
template <int L0>
__device__ __forceinline__ float2 qform2(const float* __restrict__ Hm, const float* __restrict__ wl,
                                         int nc) {
    const float* ha = Hm + ((size_t)L0 * NN + nc) * 64;
    const float* hb = Hm + ((size_t)(L0 + 1) * NN + nc) * 64;
    float4 ua[16], ub[16];
#pragma unroll
    for (int q = 0; q < 16; ++q) {
        ua[q] = {0.f, 0.f, 0.f, 0.f};
        ub[q] = {0.f, 0.f, 0.f, 0.f};
    }
    for (int dq = 0; dq < 16; ++dq) {
        float4 h4a = *(const float4*)(ha + dq * 4);
        float4 h4b = *(const float4*)(hb + dq * 4);
        const float* m0 = wl + dq * 256;  // 4 consecutive M rows
#pragma unroll
        for (int q = 0; q < 16; ++q) {
            float4 A = *(const float4*)(m0 + q * 4);
            float4 B = *(const float4*)(m0 + 64 + q * 4);
            float4 C = *(const float4*)(m0 + 128 + q * 4);
            float4 D = *(const float4*)(m0 + 192 + q * 4);
            ua[q].x = fmaf(h4a.x, A.x, ua[q].x); ua[q].y = fmaf(h4a.x, A.y, ua[q].y);
            ua[q].z = fmaf(h4a.x, A.z, ua[q].z); ua[q].w = fmaf(h4a.x, A.w, ua[q].w);
            ua[q].x = fmaf(h4a.y, B.x, ua[q].x); ua[q].y = fmaf(h4a.y, B.y, ua[q].y);
            ua[q].z = fmaf(h4a.y, B.z, ua[q].z); ua[q].w = fmaf(h4a.y, B.w, ua[q].w);
            ua[q].x = fmaf(h4a.z, C.x, ua[q].x); ua[q].y = fmaf(h4a.z, C.y, ua[q].y);
            ua[q].z = fmaf(h4a.z, C.z, ua[q].z); ua[q].w = fmaf(h4a.z, C.w, ua[q].w);
            ua[q].x = fmaf(h4a.w, D.x, ua[q].x); ua[q].y = fmaf(h4a.w, D.y, ua[q].y);
            ua[q].z = fmaf(h4a.w, D.z, ua[q].z); ua[q].w = fmaf(h4a.w, D.w, ua[q].w);
            ub[q].x = fmaf(h4b.x, A.x, ub[q].x); ub[q].y = fmaf(h4b.x, A.y, ub[q].y);
            ub[q].z = fmaf(h4b.x, A.z, ub[q].z); ub[q].w = fmaf(h4b.x, A.w, ub[q].w);
            ub[q].x = fmaf(h4b.y, B.x, ub[q].x); ub[q].y = fmaf(h4b.y, B.y, ub[q].y);
            ub[q].z = fmaf(h4b.y, B.z, ub[q].z); ub[q].w = fmaf(h4b.y, B.w, ub[q].w);
            ub[q].x = fmaf(h4b.z, C.x, ub[q].x); ub[q].y = fmaf(h4b.z, C.y, ub[q].y);
            ub[q].z = fmaf(h4b.z, C.z, ub[q].z); ub[q].w = fmaf(h4b.z, C.w, ub[q].w);
            ub[q].x = fmaf(h4b.w, D.x, ub[q].x); ub[q].y = fmaf(h4b.w, D.y, ub[q].y);
            ub[q].z = fmaf(h4b.w, D.z, ub[q].z); ub[q].w = fmaf(h4b.w, D.w, ub[q].w);
        }
    }
    float sa = 0.f, sb = 0.f;
#pragma unroll
    for (int dq = 0; dq < 16; ++dq) {
        float4 h4a = *(const float4*)(ha + dq * 4);
        float4 h4b = *(const float4*)(hb + dq * 4);
        sa += ua[dq].x * h4a.x + ua[dq].y * h4a.y + ua[dq].z * h4a.z + ua[dq].w * h4a.w;
        sb += ub[dq].x * h4b.x + ub[dq].y * h4b.y + ub[dq].z * h4b.z + ub[dq].w * h4b.w;
    }
    return {sa, sb};
}

// ---------------- fused scores+softmax+hsum+out: one node per thread ----------------
// Only M (16KB) + Wout (10KB) in LDS; every LDS read is a wave-broadcast (zero conflicts).
__global__ __launch_bounds__(256) void k_scoresum(const float* __restrict__ Hm, const float* __restrict__ Mm,
                                                  const float* __restrict__ Wout, const float* __restrict__ bout,
                                                  float* __restrict__ out) {
    __shared__ float wl[4096];
    __shared__ float wo[64 * CC];
    const int t = threadIdx.x;
    for (int i = t; i < 1024; i += 256) ((float4*)wl)[i] = ((const float4*)Mm)[i];
    for (int i = t; i < 640; i += 256) ((float4*)wo)[i] = ((const float4*)Wout)[i];
    __syncthreads();
    const int n = blockIdx.x * 256 + t;
    const int nc = n < NN ? n : NN - 1;

    float2 s01 = qform2<0>(Hm, wl, nc);
    float2 s23 = qform2<2>(Hm, wl, nc);

    float s0 = s01.x * 10.f, s1 = s01.y * 10.f, s2 = s23.x * 10.f, s3 = s23.y * 10.f;
    float m = fmaxf(fmaxf(s0, s1), fmaxf(s2, s3));
    float e0 = __expf(s0 - m), e1 = __expf(s1 - m), e2 = __expf(s2 - m), e3 = __expf(s3 - m);
    float inv = 1.f / (e0 + e1 + e2 + e3);
    float w0 = e0 * inv, w1 = e1 * inv, w2 = e2 * inv, w3 = e3 * inv;

    // hsum in registers (statically indexed)
    const float* h0p = Hm + ((size_t)0 * NN + nc) * 64;
    const float* h1p = Hm + ((size_t)1 * NN + nc) * 64;
    const float* h2p = Hm + ((size_t)2 * NN + nc) * 64;
    const float* h3p = Hm + ((size_t)3 * NN + nc) * 64;
    float4 hs[16];
#pragma unroll
    for (int dq = 0; dq < 16; ++dq) {
        float4 a = *(const float4*)(h0p + dq * 4);
        float4 b = *(const float4*)(h1p + dq * 4);
        float4 c = *(const float4*)(h2p + dq * 4);
        float4 d = *(const float4*)(h3p + dq * 4);
        hs[dq].x = w0 * a.x + w1 * b.x + w2 * c.x + w3 * d.x;
        hs[dq].y = w0 * a.y + w1 * b.y + w2 * c.y + w3 * d.y;
        hs[dq].z = w0 * a.z + w1 * b.z + w2 * c.z + w3 * d.z;
        hs[dq].w = w0 * a.w + w1 * b.w + w2 * c.w + w3 * d.w;
    }
    // out GEMV: 40 outputs in 10 float4 accumulators; Wout rows broadcast from LDS
    float4 acc[10];
#pragma unroll
    for (int j = 0; j < 10; ++j) acc[j] = {0.f, 0.f, 0.f, 0.f};
#pragma unroll
    for (int dq = 0; dq < 16; ++dq) {
#pragma unroll
        for (int r = 0; r < 4; ++r) {
            float hd = r == 0 ? hs[dq].x : (r == 1 ? hs[dq].y : (r == 2 ? hs[dq].z : hs[dq].w));
            const float* wrow = wo + (dq * 4 + r) * CC;
#pragma unroll
            for (int j = 0; j < 10; ++j) {
                float4 w = *(const float4*)(wrow + j * 4);
                acc[j].x = fmaf(hd, w.x, acc[j].x);
                acc[j].y = fmaf(hd, w.y, acc[j].y);
                acc[j].z = fmaf(hd, w.z, acc[j].z);
                acc[j].w = fmaf(hd, w.w, acc[j].w);
            }
        }
    }
    if (n < NN) {
        float* op = out + (size_t)n * CC;
#pragma unroll
        for (int j = 0; j < 10; ++j) {
            float4 b = *(const float4*)(bout + j * 4);
            float4 o = {acc[j].x + b.x, acc[j].y + b.y, acc[j].z + b.z, acc[j].w + b.w};
            *(float4*)(op + j * 4) = o;
        }
    }
}

// ---------------- host ----------------
extern "C" void kernel_launch(void* const* d_in, const int* in_sizes, int n_in,
                              void* d_out, int out_size, void* d_ws, size_t ws_size,
                              hipStream_t stream) {
    const float* x    = (const float*)d_in[0];
    const int*   ei   = (const int*)d_in[1];
    const float* W0   = (const float*)d_in[2];
    const float* b0   = (const float*)d_in[3];
    const float* Ws   = (const float*)d_in[4];
    const float* bs   = (const float*)d_in[5];
    const float* Wq   = (const float*)d_in[6];
    const float* Wk   = (const float*)d_in[7];
    const float* Wout = (const float*)d_in[8];
    const float* bout = (const float*)d_in[9];
    float* out = (float*)d_out;

    char* p = (char*)d_ws;
    auto carve = [&](size_t bytes) {
        void* r = (void*)p;
        p += (bytes + 255) & ~(size_t)255;
        return r;
    };
    int*   deg     = (int*)carve((size_t)NN * 4);
    float* dinv    = (float*)carve((size_t)NN * 4);
    int*   row_ptr = (int*)carve((size_t)(NN + 1) * 4);
    int*   bsum    = (int*)carve(256 * 4);
    int*   bcnt    = (int*)carve(NBUK * 4);
    u64*   bpr     = (u64*)carve((size_t)NBUK * BCAP3 * 8);
    int*   cs      = (int*)carve((size_t)(EE + NN) * 4);
    float* M       = (float*)carve((size_t)HH * HH * 4);
    float* z       = (float*)carve((size_t)NN * HH * 4);
    float* Hm      = (float*)carve((size_t)4 * NN * HH * 4);
    (void)ws_size; (void)n_in; (void)in_sizes; (void)out_size;

    const int GB_N = (NN + 255) / 256;
    const int GT   = (NN + 63) / 64;     // 1563
    const int GP   = NN / 16;            // 6250
    const int GSS  = (NN + 255) / 256;   // 391

    k_init<<<1, 128, 0, stream>>>(bcnt);
    k_bucket<<<ABLK, 256, 0, stream>>>(ei, bcnt, bpr);
    k_count3<<<NBUK, 512, 0, stream>>>(bpr, bcnt, deg);
    k_dinv<<<GB_N, 256, 0, stream>>>(deg, dinv);
    k_scanA<<<NB, SCAN_B, 0, stream>>>(deg, row_ptr, bsum);
    k_scanB<<<1, 128, 0, stream>>>(bsum);
    k_scanC<<<NB, SCAN_B, 0, stream>>>(row_ptr, bsum);
    k_fill3<<<NBUK, 512, 0, stream>>>(bpr, bcnt, row_ptr, cs);
    k_prepM<<<16, 256, 0, stream>>>(Wq, Wk, M);

    k_gemm<FF><<<GT, 256, 0, stream>>>(x, W0, dinv, z, NN);
    k_prop<<<GP, 256, 0, stream>>>(z, row_ptr, cs, dinv, b0, Hm);
    for (int l = 1; l < 4; ++l) {
        k_gemm<HH><<<GT, 256, 0, stream>>>(Hm + (size_t)(l - 1) * NN * HH,
                                           Ws + (size_t)(l - 1) * HH * HH, dinv, z, NN);
        k_prop<<<GP, 256, 0, stream>>>(z, row_ptr, cs, dinv, bs + (size_t)(l - 1) * HH,
                                       Hm + (size_t)l * NN * HH);
    }

    k_scoresum<<<GSS, 256, 0, stream>>>(Hm, M, Wout, bout, out);
}

// Round 12
// 585.084 us; speedup vs baseline: 1.0730x; 1.0730x over previous
//
#include <hip/hip_runtime.h>
#include <hip/hip_bf16.h>
#include <math.h>

#define NN 100000
#define EE 1600000
#define FF 128
#define HH 64
#define CC 40

constexpr int SCAN_B = 1024;
constexpr int NB = (NN + SCAN_B - 1) / SCAN_B;  // 98

typedef unsigned long long u64;
typedef float f32x4 __attribute__((ext_vector_type(4)));

// 125 dst-range buckets of 800 nodes each (125*800 == 100000 exactly).
constexpr int NBUK = 125;
constexpr int RNB = 800;
constexpr int BCAP3 = 13800;
constexpr int NE_BLK = 4000;
constexpr int ABLK = EE / NE_BLK;   // 400 blocks

__global__ void k_init(int* __restrict__ bcnt) {
    int i = threadIdx.x;
    if (i < NBUK) bcnt[i] = 0;
}

__global__ __launch_bounds__(256) void k_bucket(const int* __restrict__ ei, int* __restrict__ bcnt,
                                                u64* __restrict__ bpr) {
    __shared__ int lcnt[NBUK], lbase[NBUK], loff[NBUK];
    const int t = threadIdx.x;
    for (int k = t; k < NBUK; k += 256) { lcnt[k] = 0; loff[k] = 0; }
    __syncthreads();
    const int e0 = blockIdx.x * NE_BLK;
    int es[16], ed[16];
#pragma unroll
    for (int k = 0; k < 16; ++k) {
        int idx = t + k * 256;
        if (idx < NE_BLK) {
            es[k] = ei[e0 + idx];
            ed[k] = ei[EE + e0 + idx];
            atomicAdd(&lcnt[ed[k] / RNB], 1);
        }
    }
    __syncthreads();
    for (int k = t; k < NBUK; k += 256) lbase[k] = atomicAdd(&bcnt[k], lcnt[k]);
    __syncthreads();
#pragma unroll
    for (int k = 0; k < 16; ++k) {
        int idx = t + k * 256;
        if (idx < NE_BLK) {
            int b = ed[k] / RNB;
            int pos = lbase[b] + atomicAdd(&loff[b], 1);
            if (pos < BCAP3) {
                bpr[(size_t)b * BCAP3 + pos] = (u64)(unsigned)es[k] | ((u64)(unsigned)ed[k] << 32);
            }
        }
    }
}

__global__ __launch_bounds__(512) void k_count3(const u64* __restrict__ bpr, const int* __restrict__ bcnt,
                                                int* __restrict__ deg) {
    __shared__ int h[RNB];
    const int t = threadIdx.x, b = blockIdx.x;
    for (int k = t; k < RNB; k += 512) h[k] = 0;
    __syncthreads();
    const int cnt = min(bcnt[b], BCAP3);
    const u64* __restrict__ pp = bpr + (size_t)b * BCAP3;
    const int lo = b * RNB;
    for (int i = t; i < cnt; i += 512) atomicAdd(&h[(int)(pp[i] >> 32) - lo], 1);
    __syncthreads();
    for (int k = t; k < RNB; k += 512) deg[lo + k] = h[k] + 1;  // +1 self-loop
}

__global__ void k_dinv(const int* __restrict__ deg, float* __restrict__ dinv) {
    int i = blockIdx.x * 256 + threadIdx.x;
    if (i < NN) dinv[i] = rsqrtf((float)deg[i]);
}

__global__ void k_scanA(const int* __restrict__ deg, int* __restrict__ excl, int* __restrict__ bsum) {
    __shared__ int s[SCAN_B];
    int t = threadIdx.x;
    int g = blockIdx.x * SCAN_B + t;
    int v = (g < NN) ? deg[g] : 0;
    s[t] = v;
    __syncthreads();
    for (int o = 1; o < SCAN_B; o <<= 1) {
        int u = (t >= o) ? s[t - o] : 0;
        __syncthreads();
        s[t] += u;
        __syncthreads();
    }
    if (g < NN) excl[g] = s[t] - v;
    if (t == SCAN_B - 1) bsum[blockIdx.x] = s[t];
}

__global__ void k_scanB(int* __restrict__ bsum) {
    __shared__ int s[128];
    int t = threadIdx.x;
    int v = (t < NB) ? bsum[t] : 0;
    s[t] = v;
    __syncthreads();
    for (int o = 1; o < 128; o <<= 1) {
        int u = (t >= o) ? s[t - o] : 0;
        __syncthreads();
        s[t] += u;
        __syncthreads();
    }
    if (t < NB) bsum[t] = s[t] - v;
}

__global__ void k_scanC(int* __restrict__ rp, const int* __restrict__ bsum) {
    int t = threadIdx.x;
    int g = blockIdx.x * SCAN_B + t;
    if (g < NN) rp[g] = rp[g] + bsum[blockIdx.x];
    if (g == 0) rp[NN] = EE + NN;
}

__global__ __launch_bounds__(512) void k_fill3(const u64* __restrict__ bpr, const int* __restrict__ bcnt,
                                               const int* __restrict__ rp, int* __restrict__ cs) {
    __shared__ int lcur[RNB];
    __shared__ int lbuf[RNB + BCAP3];
    const int t = threadIdx.x, b = blockIdx.x;
    const int lo = b * RNB;
    const int rpl = rp[lo];
    for (int k = t; k < RNB; k += 512) lcur[k] = rp[lo + k] - rpl;
    __syncthreads();
    const int cnt = min(bcnt[b], BCAP3);
    const u64* __restrict__ pp = bpr + (size_t)b * BCAP3;
    for (int i = t; i < cnt; i += 512) {
        u64 u = pp[i];
        int pos = atomicAdd(&lcur[(int)(u >> 32) - lo], 1);
        lbuf[pos] = (int)(unsigned)u;
    }
    __syncthreads();
    for (int k = t; k < RNB; k += 512) {
        int pos = atomicAdd(&lcur[k], 1);
        lbuf[pos] = lo + k;
    }
    __syncthreads();
    const int total = rp[lo + RNB] - rpl;
    for (int i = t; i < total; i += 512) __builtin_nontemporal_store(lbuf[i], cs + rpl + i);
}

template <int K>
__global__ __launch_bounds__(256) void k_gemm(const float* __restrict__ A, const float* __restrict__ W,
                                              const float* __restrict__ dinv, float* __restrict__ Z,
                                              int nrows) {
    constexpr int S = 68;
    __shared__ float wl[64 * 64];
    __shared__ float hl[64 * S];
    const int t = threadIdx.x;
    const int r0 = blockIdx.x * 64;
    const int rg = t >> 4, cg = t & 15;
    float acc[4][4] = {};

    for (int kb = 0; kb < K; kb += 64) {
        {
            const float4* Wv = (const float4*)(W + kb * 64);
            for (int i = t; i < 1024; i += 256) ((float4*)wl)[i] = Wv[i];
        }
        for (int i = t; i < 1024; i += 256) {
            int row = i >> 4, d4 = i & 15;
            float4 v = {0.f, 0.f, 0.f, 0.f};
            if (r0 + row < nrows) v = *(const float4*)(A + (size_t)(r0 + row) * K + kb + d4 * 4);
            *(float4*)(hl + row * S + d4 * 4) = v;
        }
        __syncthreads();
#pragma unroll 8
        for (int d = 0; d < 64; ++d) {
            float4 w4 = *(const float4*)(wl + d * 64 + cg * 4);
#pragma unroll
            for (int i = 0; i < 4; i++) {
                float h = hl[(rg * 4 + i) * S + d];
                acc[i][0] = fmaf(h, w4.x, acc[i][0]);
                acc[i][1] = fmaf(h, w4.y, acc[i][1]);
                acc[i][2] = fmaf(h, w4.z, acc[i][2]);
                acc[i][3] = fmaf(h, w4.w, acc[i][3]);
            }
        }
        __syncthreads();
    }
#pragma unroll
    for (int i = 0; i < 4; i++) {
        int row = r0 + rg * 4 + i;
        if (row < nrows) {
            float dv = dinv[row];
            float4 o = {acc[i][0] * dv, acc[i][1] * dv, acc[i][2] * dv, acc[i][3] * dv};
            *(float4*)(Z + (size_t)row * 64 + cg * 4) = o;
        }
    }
}

// ---------------- M = (Wq @ Wk^T) * (1/TEMP)  (64x64), 16 blocks x 4 rows ----------------
__global__ __launch_bounds__(256) void k_prepM(const float* __restrict__ Wq, const float* __restrict__ Wk,
                                               float* __restrict__ M) {
    __shared__ float wk[64 * 65];
    __shared__ float wq[4 * 64];
    const int t = threadIdx.x;
    for (int i = t; i < 1024; i += 256) {
        int r = i >> 4, c4 = i & 15;
        float4 v = ((const float4*)Wk)[i];
        wk[r * 65 + c4 * 4 + 0] = v.x;
        wk[r * 65 + c4 * 4 + 1] = v.y;
        wk[r * 65 + c4 * 4 + 2] = v.z;
        wk[r * 65 + c4 * 4 + 3] = v.w;
    }
    const int rbase = blockIdx.x * 4;
    wq[t] = Wq[rbase * 64 + t];
    __syncthreads();
    const int rr = t >> 6;
    const int c = t & 63;
    float acc = 0.f;
#pragma unroll 8
    for (int e = 0; e < 64; ++e) acc = fmaf(wq[rr * 64 + e], wk[c * 65 + e], acc);
    M[(rbase + rr) * 64 + c] = acc * 10.f;  // fold 1/TEMP
}

// ---------------- scores[r] = h_r @ M @ h_r^T (GEMM tile + fused dot; R8 structure) ----------------
__global__ __launch_bounds__(256) void k_score(const float* __restrict__ Hm, const float* __restrict__ M,
                                               float* __restrict__ scores) {
    constexpr int S = 68;
    __shared__ float wl[4096];
    __shared__ float hl[64 * S];
    const int t = threadIdx.x;
    const int r0 = blockIdx.x * 64;  // 4N = 400000 = 6250*64, no tail
    for (int i = t; i < 1024; i += 256) ((float4*)wl)[i] = ((const float4*)M)[i];
    for (int i = t; i < 1024; i += 256) {
        int row = i >> 4, d4 = i & 15;
        *(float4*)(hl + row * S + d4 * 4) = *(const float4*)(Hm + (size_t)(r0 + row) * 64 + d4 * 4);
    }
    __syncthreads();
    const int rg = t >> 4, cg = t & 15;
    float u[4][4] = {};
#pragma unroll 8
    for (int d = 0; d < 64; ++d) {
        float4 m4 = *(const float4*)(wl + d * 64 + cg * 4);
#pragma unroll
        for (int i = 0; i < 4; i++) {
            float h = hl[(rg * 4 + i) * S + d];
            u[i][0] = fmaf(h, m4.x, u[i][0]);
            u[i][1] = fmaf(h, m4.y, u[i][1]);
            u[i][2] = fmaf(h, m4.z, u[i][2]);
            u[i][3] = fmaf(h, m4.w, u[i][3]);
        }
    }
#pragma unroll
    for (int i = 0; i < 4; i++) {
        const float* hrow = hl + (rg * 4 + i) * S + cg * 4;
        float p = u[i][0] * hrow[0] + u[i][1] * hrow[1] + u[i][2] * hrow[2] + u[i][3] * hrow[3];
        p += __shfl_xor(p, 1);
        p += __shfl_xor(p, 2);
        p += __shfl_xor(p, 4);
        p += __shfl_xor(p, 8);
        if (cg == 0) scores[r0 + rg * 4 + i] = p;  // already has 1/TEMP folded in
    }
}

__global__ __launch_bounds__(256) void k_prop(const float* __restrict__ z, const int* __restrict__ rp,
                                              const int* __restrict__ cs, const float* __restrict__ dinv,
                                              const float* __restrict__ bias, float* __restrict__ out) {
    const int lane = threadIdx.x & 63;
    const int g = lane >> 4;
    const int l4 = lane & 15;
    const int n = blockIdx.x * 16 + (threadIdx.x >> 6) * 4 + g;
    const int beg = rp[n], end = rp[n + 1];
    float4 a0 = {0, 0, 0, 0}, a1 = {0, 0, 0, 0}, a2 = {0, 0, 0, 0}, a3 = {0, 0, 0, 0};
    int i = beg;
    for (; i + 8 <= end; i += 8) {
        int c0 = __builtin_nontemporal_load(cs + i);
        int c1 = __builtin_nontemporal_load(cs + i + 1);
        int c2 = __builtin_nontemporal_load(cs + i + 2);
        int c3 = __builtin_nontemporal_load(cs + i + 3);
        int c4 = __builtin_nontemporal_load(cs + i + 4);
        int c5 = __builtin_nontemporal_load(cs + i + 5);
        int c6 = __builtin_nontemporal_load(cs + i + 6);
        int c7 = __builtin_nontemporal_load(cs + i + 7);
        float4 z0 = *(const float4*)(z + (size_t)(unsigned)c0 * 64 + l4 * 4);
        float4 z1 = *(const float4*)(z + (size_t)(unsigned)c1 * 64 + l4 * 4);
        float4 z2 = *(const float4*)(z + (size_t)(unsigned)c2 * 64 + l4 * 4);
        float4 z3 = *(const float4*)(z + (size_t)(unsigned)c3 * 64 + l4 * 4);
        float4 z4 = *(const float4*)(z + (size_t)(unsigned)c4 * 64 + l4 * 4);
        float4 z5 = *(const float4*)(z + (size_t)(unsigned)c5 * 64 + l4 * 4);
        float4 z6 = *(const float4*)(z + (size_t)(unsigned)c6 * 64 + l4 * 4);
        float4 z7 = *(const float4*)(z + (size_t)(unsigned)c7 * 64 + l4 * 4);
        a0.x += z0.x; a0.y += z0.y; a0.z += z0.z; a0.w += z0.w;
        a1.x += z1.x; a1.y += z1.y; a1.z += z1.z; a1.w += z1.w;
        a2.x += z2.x; a2.y += z2.y; a2.z += z2.z; a2.w += z2.w;
        a3.x += z3.x; a3.y += z3.y; a3.z += z3.z; a3.w += z3.w;
        a0.x += z4.x; a0.y += z4.y; a0.z += z4.z; a0.w += z4.w;
        a1.x += z5.x; a1.y += z5.y; a1.z += z5.z; a1.w += z5.w;
        a2.x += z6.x; a2.y += z6.y; a2.z += z6.z; a2.w += z6.w;
        a3.x += z7.x; a3.y += z7.y; a3.z += z7.z; a3.w += z7.w;
    }
    for (; i + 4 <= end; i += 4) {
        int c0 = __builtin_nontemporal_load(cs + i);
        int c1 = __builtin_nontemporal_load(cs + i + 1);
        int c2 = __builtin_nontemporal_load(cs + i + 2);
        int c3 = __builtin_nontemporal_load(cs + i + 3);
        float4 z0 = *(const float4*)(z + (size_t)(unsigned)c0 * 64 + l4 * 4);
        float4 z1 = *(const float4*)(z + (size_t)(unsigned)c1 * 64 + l4 * 4);
        float4 z2 = *(const float4*)(z + (size_t)(unsigned)c2 * 64 + l4 * 4);
        float4 z3 = *(const float4*)(z + (size_t)(unsigned)c3 * 64 + l4 * 4);
        a0.x += z0.x; a0.y += z0.y; a0.z += z0.z; a0.w += z0.w;
        a1.x += z1.x; a1.y += z1.y; a1.z += z1.z; a1.w += z1.w;
        a2.x += z2.x; a2.y += z2.y; a2.z += z2.z; a2.w += z2.w;
        a3.x += z3.x; a3.y += z3.y; a3.z += z3.z; a3.w += z3.w;
    }
    for (; i < end; ++i) {
        int c = __builtin_nontemporal_load(cs + i);
        float4 zr = *(const float4*)(z + (size_t)(unsigned)c * 64 + l4 * 4);
        a0.x += zr.x; a0.y += zr.y; a0.z += zr.z; a0.w += zr.w;
    }
    const float dn = dinv[n];
    const float4 b4 = *(const float4*)(bias + l4 * 4);
    float4 r;
    r.x = fmaf(dn, (a0.x + a1.x) + (a2.x + a3.x), b4.x);
    r.y = fmaf(dn, (a0.y + a1.y) + (a2.y + a3.y), b4.y);
    r.z = fmaf(dn, (a0.z + a1.z) + (a2.z + a3.z), b4.z);
    r.w = fmaf(dn, (a0.w + a1.w) + (a2.w + a3.w), b4.w);
    r.x = r.x > 0.f ? r.x : 0.f;
    r.y = r.y > 0.f ? r.y : 0.f;
    r.z = r.z > 0.f ? r.z : 0.f;
    r.w = r.w > 0.f ? r.w : 0.f;
    __builtin_nontemporal_store(*(const f32x4*)&r, (f32x4*)(out + (size_t)n * 64 + l4 * 4));
}

// ---------------- summarize (tiled, R8 structure): 64 nodes/block ----------------
__global__ __launch_bounds__(256) void k_sum(const float* __restrict__ Hm, const float* __restrict__ scores,
                                             const float* __restrict__ Wout, const float* __restrict__ bout,
                                             float* __restrict__ out) {
    __shared__ float wo[64 * CC];
    __shared__ float hs[64][68];
    __shared__ float wl4[4][64];
    const int t = threadIdx.x;
    const int r0 = blockIdx.x * 64;
    for (int i = t; i < (64 * CC) / 4; i += 256) ((float4*)wo)[i] = ((const float4*)Wout)[i];
    if (t < 64) {
        int n = r0 + t;
        float s0 = 0.f, s1 = 0.f, s2 = 0.f, s3 = 0.f;
        if (n < NN) {
            s0 = scores[0 * NN + n];  // 1/TEMP already folded into M
            s1 = scores[1 * NN + n];
            s2 = scores[2 * NN + n];
            s3 = scores[3 * NN + n];
        }
        float m = fmaxf(fmaxf(s0, s1), fmaxf(s2, s3));
        float e0 = __expf(s0 - m), e1 = __expf(s1 - m), e2 = __expf(s2 - m), e3 = __expf(s3 - m);
        float inv = 1.f / (e0 + e1 + e2 + e3);
        wl4[0][t] = e0 * inv;
        wl4[1][t] = e1 * inv;
        wl4[2][t] = e2 * inv;
        wl4[3][t] = e3 * inv;
    }
    __syncthreads();
    for (int i = t; i < 1024; i += 256) {
        int row = i >> 4, d4 = i & 15;
        int n = r0 + row;
        float4 acc = {0.f, 0.f, 0.f, 0.f};
        if (n < NN) {
#pragma unroll
            for (int l = 0; l < 4; ++l) {
                float w = wl4[l][row];
                float4 h = *(const float4*)(Hm + ((size_t)l * NN + n) * 64 + d4 * 4);
                acc.x = fmaf(w, h.x, acc.x);
                acc.y = fmaf(w, h.y, acc.y);
                acc.z = fmaf(w, h.z, acc.z);
                acc.w = fmaf(w, h.w, acc.w);
            }
        }
        *(float4*)(&hs[row][d4 * 4]) = acc;
    }
    __syncthreads();
    const int row = t >> 2, cg = t & 3;
    float2 acc2[5] = {};
    for (int d = 0; d < 64; ++d) {
        float a = hs[row][d];
        const float2* wrow = (const float2*)(wo + d * CC + cg * 10);
#pragma unroll
        for (int j = 0; j < 5; ++j) {
            float2 w = wrow[j];
            acc2[j].x = fmaf(a, w.x, acc2[j].x);
            acc2[j].y = fmaf(a, w.y, acc2[j].y);
        }
    }
    int n = r0 + row;
    if (n < NN) {
        float* op = out + (size_t)n * CC + cg * 10;
        const float* bp = bout + cg * 10;
#pragma unroll
        for (int j = 0; j < 5; ++j) {
            float2 b = *(const float2*)(bp + 2 * j);
            float2 o = {acc2[j].x + b.x, acc2[j].y + b.y};
            *(float2*)(op + 2 * j) = o;
        }
    }
}

// ---------------- host ----------------
extern "C" void kernel_launch(void* const* d_in, const int* in_sizes, int n_in,
                              void* d_out, int out_size, void* d_ws, size_t ws_size,
                              hipStream_t stream) {
    const float* x    = (const float*)d_in[0];
    const int*   ei   = (const int*)d_in[1];
    const float* W0   = (const float*)d_in[2];
    const float* b0   = (const float*)d_in[3];
    const float* Ws   = (const float*)d_in[4];
    const float* bs   = (const float*)d_in[5];
    const float* Wq   = (const float*)d_in[6];
    const float* Wk   = (const float*)d_in[7];
    const float* Wout = (const float*)d_in[8];
    const float* bout = (const float*)d_in[9];
    float* out = (float*)d_out;

    char* p = (char*)d_ws;
    auto carve = [&](size_t bytes) {
        void* r = (void*)p;
        p += (bytes + 255) & ~(size_t)255;
        return r;
    };
    int*   deg     = (int*)carve((size_t)NN * 4);
    float* dinv    = (float*)carve((size_t)NN * 4);
    int*   row_ptr = (int*)carve((size_t)(NN + 1) * 4);
    int*   bsum    = (int*)carve(256 * 4);
    int*   bcnt    = (int*)carve(NBUK * 4);
    u64*   bpr     = (u64*)carve((size_t)NBUK * BCAP3 * 8);
    int*   cs      = (int*)carve((size_t)(EE + NN) * 4);
    float* M       = (float*)carve((size_t)HH * HH * 4);
    float* z       = (float*)carve((size_t)NN * HH * 4);
    float* Hm      = (float*)carve((size_t)4 * NN * HH * 4);
    float* scores  = (float*)carve((size_t)4 * NN * 4);
    (void)ws_size; (void)n_in; (void)in_sizes; (void)out_size;

    const int GB_N = (NN + 255) / 256;
    const int GT   = (NN + 63) / 64;     // 1563
    const int GP   = NN / 16;            // 6250
    const int GSC  = (4 * NN) / 64;      // 6250
    const int GS2  = (NN + 63) / 64;     // 1563

    k_init<<<1, 128, 0, stream>>>(bcnt);
    k_bucket<<<ABLK, 256, 0, stream>>>(ei, bcnt, bpr);
    k_count3<<<NBUK, 512, 0, stream>>>(bpr, bcnt, deg);
    k_dinv<<<GB_N, 256, 0, stream>>>(deg, dinv);
    k_scanA<<<NB, SCAN_B, 0, stream>>>(deg, row_ptr, bsum);
    k_scanB<<<1, 128, 0, stream>>>(bsum);
    k_scanC<<<NB, SCAN_B, 0, stream>>>(row_ptr, bsum);
    k_fill3<<<NBUK, 512, 0, stream>>>(bpr, bcnt, row_ptr, cs);
    k_prepM<<<16, 256, 0, stream>>>(Wq, Wk, M);

    k_gemm<FF><<<GT, 256, 0, stream>>>(x, W0, dinv, z, NN);
    k_prop<<<GP, 256, 0, stream>>>(z, row_ptr, cs, dinv, b0, Hm);
    for (int l = 1; l < 4; ++l) {
        k_gemm<HH><<<GT, 256, 0, stream>>>(Hm + (size_t)(l - 1) * NN * HH,
                                           Ws + (size_t)(l - 1) * HH * HH, dinv, z, NN);
        k_prop<<<GP, 256, 0, stream>>>(z, row_ptr, cs, dinv, bs + (size_t)(l - 1) * HH,
                                       Hm + (size_t)l * NN * HH);
    }

    k_score<<<GSC, 256, 0, stream>>>(Hm, M, scores);
    k_sum<<<GS2, 256, 0, stream>>>(Hm, scores, Wout, bout, out);
}